// Round 6
// baseline (27479.169 us; speedup 1.0000x reference)
//
#include <hip/hip_runtime.h>

#define T_DIM 512
#define B_DIM 256
#define S_DIMS 64
#define A_DIMS 16
#define E_DIM 128
#define H_DIM 512
#define X_DIM 384   // 3*E
#define G_DIM 1536  // 3*H

typedef __attribute__((ext_vector_type(8))) short short8;
typedef __attribute__((ext_vector_type(4))) float f32x4;

#define MFMA16(a, b, c) __builtin_amdgcn_mfma_f32_16x16x32_bf16(a, b, c, 0, 0, 0)

__device__ __forceinline__ float gelu_tanh(float x) {
    const float c = 0.7978845608028654f; // sqrt(2/pi)
    float x3 = x * x * x;
    return 0.5f * x * (1.0f + tanhf(c * (x + 0.044715f * x3)));
}

__device__ __forceinline__ float sigmoidf(float x) {
    return 1.0f / (1.0f + expf(-x));
}

// round-to-nearest-even fp32 -> bf16 (as ushort)
__device__ __forceinline__ unsigned short f2bf(float x) {
    unsigned u = __float_as_uint(x);
    u += 0x7FFFu + ((u >> 16) & 1u);
    return (unsigned short)(u >> 16);
}
__device__ __forceinline__ float bf2f(unsigned short b) {
    return __uint_as_float(((unsigned)b) << 16);
}

// ---------------- one-time: W[k][n] fp32 -> W^T[n][k] bf16 hi/lo
__global__ __launch_bounds__(256) void split_transpose(
    const float* __restrict__ w, int K, int N,
    unsigned short* __restrict__ t_hi, unsigned short* __restrict__ t_lo)
{
    __shared__ float tile[32][33];
    int k0 = blockIdx.x * 32, n0 = blockIdx.y * 32;
    int tid = threadIdx.x;
    #pragma unroll
    for (int p = 0; p < 4; ++p) {
        int i = tid + p * 256; int r = i >> 5, c = i & 31;
        tile[r][c] = w[(size_t)(k0 + r) * N + n0 + c];
    }
    __syncthreads();
    #pragma unroll
    for (int p = 0; p < 4; ++p) {
        int i = tid + p * 256; int r = i >> 5, c = i & 31; // r: n-local, c: k-local
        float v = tile[c][r];
        unsigned short hi = f2bf(v);
        size_t o = (size_t)(n0 + r) * K + k0 + c;
        t_hi[o] = hi;
        t_lo[o] = f2bf(v - bf2f(hi));
    }
}

// ---------------- Embedding: x = [gelu(s@Ws+bs), gelu(a@Wa+ba), gelu(r@Wr+br)]
// writes x as bf16 hi/lo, [rows][384]
__global__ __launch_bounds__(256) void embed_kernel(
    const float* __restrict__ s, const float* __restrict__ a, const float* __restrict__ r,
    const float* __restrict__ Ws, const float* __restrict__ bs,
    const float* __restrict__ Wa, const float* __restrict__ ba,
    const float* __restrict__ Wr, const float* __restrict__ br,
    unsigned short* __restrict__ x_hi, unsigned short* __restrict__ x_lo)
{
    __shared__ float Ws_s[64][128];
    __shared__ float Wa_s[16][128];
    __shared__ float Wr_s[128], bs_s[128], ba_s[128], br_s[128];
    __shared__ float s_s[64][64];
    __shared__ float a_s[64][16];
    __shared__ float r_s[64];
    int tid = threadIdx.x;
    for (int i = tid; i < 64 * 128; i += 256) Ws_s[i >> 7][i & 127] = Ws[i];
    for (int i = tid; i < 16 * 128; i += 256) Wa_s[i >> 7][i & 127] = Wa[i];
    if (tid < 128) { Wr_s[tid] = Wr[tid]; bs_s[tid] = bs[tid]; ba_s[tid] = ba[tid]; br_s[tid] = br[tid]; }
    size_t row0 = (size_t)blockIdx.x * 64;
    for (int i = tid; i < 64 * 64; i += 256) s_s[i >> 6][i & 63] = s[row0 * 64 + i];
    for (int i = tid; i < 64 * 16; i += 256) a_s[i >> 4][i & 15] = a[row0 * 16 + i];
    if (tid < 64) r_s[tid] = r[row0 + tid];
    __syncthreads();
    int e = tid & 127, ty = tid >> 7;
    for (int rw = ty; rw < 64; rw += 2) {
        float accS = bs_s[e];
        #pragma unroll
        for (int k = 0; k < 64; ++k) accS += s_s[rw][k] * Ws_s[k][e];
        float accA = ba_s[e];
        #pragma unroll
        for (int k = 0; k < 16; ++k) accA += a_s[rw][k] * Wa_s[k][e];
        float accR = br_s[e] + r_s[rw] * Wr_s[e];
        float v0 = gelu_tanh(accS);
        float v1 = gelu_tanh(accA);
        float v2 = gelu_tanh(accR);
        size_t base = (row0 + rw) * X_DIM;
        unsigned short h0 = f2bf(v0), h1 = f2bf(v1), h2 = f2bf(v2);
        x_hi[base + e] = h0;        x_lo[base + e] = f2bf(v0 - bf2f(h0));
        x_hi[base + 128 + e] = h1;  x_lo[base + 128 + e] = f2bf(v1 - bf2f(h1));
        x_hi[base + 256 + e] = h2;  x_lo[base + 256 + e] = f2bf(v2 - bf2f(h2));
    }
}

// ---------------- Gates GEMM (MFMA): gx[m][n] = x[m][:] . wiT[n][:] + bias[n]
// grid (12, rows/128): x = N-block (fastest -> A-tile L2 reuse), y = M-block.
// 256 thr = 4 waves (2M x 2N), wave-tile 64x64, 4x4 fragments.
__global__ __launch_bounds__(256) void gates_mfma(
    const unsigned short* __restrict__ x_hi, const unsigned short* __restrict__ x_lo,
    const unsigned short* __restrict__ wiT_hi, const unsigned short* __restrict__ wiT_lo,
    const float* __restrict__ bias, float* __restrict__ C)
{
    const int tid = threadIdx.x;
    const int lane = tid & 63;
    const int wv = tid >> 6;
    const int wm = wv >> 1, wn = wv & 1;
    const size_t m0 = (size_t)blockIdx.y * 128 + wm * 64;
    const int n0 = blockIdx.x * 128 + wn * 64;
    const int lr = lane & 15, lk = (lane >> 4) * 8;
    f32x4 acc[4][4] = {};
    for (int k0 = 0; k0 < X_DIM; k0 += 32) {
        short8 ahi[4], alo[4], bhi[4], blo[4];
        #pragma unroll
        for (int i = 0; i < 4; ++i) {
            size_t oa = (m0 + i * 16 + lr) * X_DIM + k0 + lk;
            ahi[i] = *reinterpret_cast<const short8*>(&x_hi[oa]);
            alo[i] = *reinterpret_cast<const short8*>(&x_lo[oa]);
            size_t ob = (size_t)(n0 + i * 16 + lr) * X_DIM + k0 + lk;
            bhi[i] = *reinterpret_cast<const short8*>(&wiT_hi[ob]);
            blo[i] = *reinterpret_cast<const short8*>(&wiT_lo[ob]);
        }
        #pragma unroll
        for (int i = 0; i < 4; ++i)
            #pragma unroll
            for (int j = 0; j < 4; ++j) {
                acc[i][j] = MFMA16(ahi[i], bhi[j], acc[i][j]);
                acc[i][j] = MFMA16(ahi[i], blo[j], acc[i][j]);
                acc[i][j] = MFMA16(alo[i], bhi[j], acc[i][j]);
            }
    }
    const int rbase = (lane >> 4) * 4;
    #pragma unroll
    for (int i = 0; i < 4; ++i)
        #pragma unroll
        for (int j = 0; j < 4; ++j) {
            int colg = n0 + j * 16 + lr;
            float b = bias[colg];
            #pragma unroll
            for (int r = 0; r < 4; ++r) {
                size_t row = m0 + i * 16 + rbase + r;
                C[row * G_DIM + colg] = acc[i][j][r] + b;
            }
        }
}

// ---------------- GRU step 1 (MFMA): zr = sigmoid(gx_zr + h @ Wzr)
// grid (16, 4): x = N-block (64 of 1024 zr-cols), y = M-block (64 of 256 rows).
// wave-tile 32x32 (2x2 fragments). Writes z (fp32) or rh = r*h (bf16 hi/lo).
__global__ __launch_bounds__(256) void gru_zr_mfma(
    const float* __restrict__ gxs,   // B x 1536
    const float* __restrict__ hprev, // B x 512 fp32 (out[t-1]) or null
    const unsigned short* __restrict__ h_hi, const unsigned short* __restrict__ h_lo,
    const unsigned short* __restrict__ whT_hi, const unsigned short* __restrict__ whT_lo, // [1536][512]
    float* __restrict__ zbuf,
    unsigned short* __restrict__ rh_hi, unsigned short* __restrict__ rh_lo)
{
    const int tid = threadIdx.x;
    const int lane = tid & 63;
    const int wv = tid >> 6;
    const int wm = wv >> 1, wn = wv & 1;
    const int m0 = blockIdx.y * 64 + wm * 32;
    const int n0 = blockIdx.x * 64 + wn * 32;   // zr col space 0..1023
    const int lr = lane & 15, lk = (lane >> 4) * 8;
    f32x4 acc[2][2] = {};
    if (hprev) {
        #pragma unroll
        for (int k0 = 0; k0 < H_DIM; k0 += 32) {
            short8 ahi[2], alo[2], bhi[2], blo[2];
            #pragma unroll
            for (int i = 0; i < 2; ++i) {
                size_t oa = (size_t)(m0 + i * 16 + lr) * H_DIM + k0 + lk;
                ahi[i] = *reinterpret_cast<const short8*>(&h_hi[oa]);
                alo[i] = *reinterpret_cast<const short8*>(&h_lo[oa]);
                size_t ob = (size_t)(n0 + i * 16 + lr) * H_DIM + k0 + lk;
                bhi[i] = *reinterpret_cast<const short8*>(&whT_hi[ob]);
                blo[i] = *reinterpret_cast<const short8*>(&whT_lo[ob]);
            }
            #pragma unroll
            for (int i = 0; i < 2; ++i)
                #pragma unroll
                for (int j = 0; j < 2; ++j) {
                    acc[i][j] = MFMA16(ahi[i], bhi[j], acc[i][j]);
                    acc[i][j] = MFMA16(ahi[i], blo[j], acc[i][j]);
                    acc[i][j] = MFMA16(alo[i], bhi[j], acc[i][j]);
                }
        }
    }
    const int rbase = (lane >> 4) * 4;
    #pragma unroll
    for (int i = 0; i < 2; ++i)
        #pragma unroll
        for (int j = 0; j < 2; ++j)
            #pragma unroll
            for (int r = 0; r < 4; ++r) {
                int row = m0 + i * 16 + rbase + r;
                int col = n0 + j * 16 + lr;
                float v = sigmoidf(gxs[(size_t)row * G_DIM + col] + acc[i][j][r]);
                if (n0 < H_DIM) {
                    zbuf[(size_t)row * H_DIM + col] = v;
                } else {
                    int c = col - H_DIM;
                    float hp = hprev ? hprev[(size_t)row * H_DIM + c] : 0.0f;
                    float rh = v * hp;
                    unsigned short hi = f2bf(rh);
                    rh_hi[(size_t)row * H_DIM + c] = hi;
                    rh_lo[(size_t)row * H_DIM + c] = f2bf(rh - bf2f(hi));
                }
            }
}

// ---------------- GRU step 2 (MFMA): a = tanh(gx_a + rh @ Wa); h = hp + z*(a-hp)
// grid (8, 4). Writes h fp32 (out) + bf16 hi/lo (next step's A operand).
__global__ __launch_bounds__(256) void gru_a_mfma(
    const float* __restrict__ gxs,   // B x 1536
    const float* __restrict__ hprev, // B x 512 fp32 or null
    const unsigned short* __restrict__ rh_hi, const unsigned short* __restrict__ rh_lo,
    const float* __restrict__ zbuf,
    const unsigned short* __restrict__ whT_hi, const unsigned short* __restrict__ whT_lo,
    float* __restrict__ hout,
    unsigned short* __restrict__ h_hi, unsigned short* __restrict__ h_lo)
{
    const int tid = threadIdx.x;
    const int lane = tid & 63;
    const int wv = tid >> 6;
    const int wm = wv >> 1, wn = wv & 1;
    const int m0 = blockIdx.y * 64 + wm * 32;
    const int n0 = blockIdx.x * 64 + wn * 32;   // a col space 0..511
    const int lr = lane & 15, lk = (lane >> 4) * 8;
    f32x4 acc[2][2] = {};
    #pragma unroll
    for (int k0 = 0; k0 < H_DIM; k0 += 32) {
        short8 ahi[2], alo[2], bhi[2], blo[2];
        #pragma unroll
        for (int i = 0; i < 2; ++i) {
            size_t oa = (size_t)(m0 + i * 16 + lr) * H_DIM + k0 + lk;
            ahi[i] = *reinterpret_cast<const short8*>(&rh_hi[oa]);
            alo[i] = *reinterpret_cast<const short8*>(&rh_lo[oa]);
            size_t ob = (size_t)(1024 + n0 + i * 16 + lr) * H_DIM + k0 + lk;
            bhi[i] = *reinterpret_cast<const short8*>(&whT_hi[ob]);
            blo[i] = *reinterpret_cast<const short8*>(&whT_lo[ob]);
        }
        #pragma unroll
        for (int i = 0; i < 2; ++i)
            #pragma unroll
            for (int j = 0; j < 2; ++j) {
                acc[i][j] = MFMA16(ahi[i], bhi[j], acc[i][j]);
                acc[i][j] = MFMA16(ahi[i], blo[j], acc[i][j]);
                acc[i][j] = MFMA16(alo[i], bhi[j], acc[i][j]);
            }
    }
    const int rbase = (lane >> 4) * 4;
    #pragma unroll
    for (int i = 0; i < 2; ++i)
        #pragma unroll
        for (int j = 0; j < 2; ++j)
            #pragma unroll
            for (int r = 0; r < 4; ++r) {
                int row = m0 + i * 16 + rbase + r;
                int col = n0 + j * 16 + lr;
                float av = tanhf(gxs[(size_t)row * G_DIM + 1024 + col] + acc[i][j][r]);
                float hp = hprev ? hprev[(size_t)row * H_DIM + col] : 0.0f;
                float z = zbuf[(size_t)row * H_DIM + col];
                float hnew = hp + z * (av - hp);
                hout[(size_t)row * H_DIM + col] = hnew;
                unsigned short hi = f2bf(hnew);
                h_hi[(size_t)row * H_DIM + col] = hi;
                h_lo[(size_t)row * H_DIM + col] = f2bf(hnew - bf2f(hi));
            }
}

extern "C" void kernel_launch(void* const* d_in, const int* in_sizes, int n_in,
                              void* d_out, int out_size, void* d_ws, size_t ws_size,
                              hipStream_t stream) {
    const float* states  = (const float*)d_in[0];
    const float* actions = (const float*)d_in[1];
    const float* rewards = (const float*)d_in[2];
    const float* Ws   = (const float*)d_in[3];
    const float* bs   = (const float*)d_in[4];
    const float* Wa   = (const float*)d_in[5];
    const float* ba   = (const float*)d_in[6];
    const float* Wr   = (const float*)d_in[7];
    const float* br   = (const float*)d_in[8];
    const float* w_i  = (const float*)d_in[9];
    const float* w_h  = (const float*)d_in[10];
    const float* bgru = (const float*)d_in[11];
    float* out = (float*)d_out;

    // ---- workspace carve-up (all region sizes multiples of 16 B)
    char* p = (char*)d_ws;
    unsigned short* whT_hi = (unsigned short*)p; p += (size_t)G_DIM * H_DIM * 2;
    unsigned short* whT_lo = (unsigned short*)p; p += (size_t)G_DIM * H_DIM * 2;
    unsigned short* wiT_hi = (unsigned short*)p; p += (size_t)G_DIM * X_DIM * 2;
    unsigned short* wiT_lo = (unsigned short*)p; p += (size_t)G_DIM * X_DIM * 2;
    float*          zbuf   = (float*)p;          p += (size_t)B_DIM * H_DIM * 4;
    unsigned short* rh_hi  = (unsigned short*)p; p += (size_t)B_DIM * H_DIM * 2;
    unsigned short* rh_lo  = (unsigned short*)p; p += (size_t)B_DIM * H_DIM * 2;
    unsigned short* h_hi   = (unsigned short*)p; p += (size_t)B_DIM * H_DIM * 2;
    unsigned short* h_lo   = (unsigned short*)p; p += (size_t)B_DIM * H_DIM * 2;
    size_t fixed = (size_t)(p - (char*)d_ws);
    size_t per_step = (size_t)B_DIM * G_DIM * 4 + (size_t)B_DIM * X_DIM * 2 * 2;
    int chunk = (int)((ws_size > fixed ? ws_size - fixed : 0) / per_step);
    if (chunk > T_DIM) chunk = T_DIM;
    if (chunk < 1) chunk = 1;
    float* gx = (float*)p;
    unsigned short* x_hi = (unsigned short*)((char*)gx + (size_t)chunk * B_DIM * G_DIM * 4);
    unsigned short* x_lo = x_hi + (size_t)chunk * B_DIM * X_DIM;

    // ---- one-time weight split/transpose
    split_transpose<<<dim3(H_DIM / 32, G_DIM / 32), 256, 0, stream>>>(w_h, H_DIM, G_DIM, whT_hi, whT_lo);
    split_transpose<<<dim3(X_DIM / 32, G_DIM / 32), 256, 0, stream>>>(w_i, X_DIM, G_DIM, wiT_hi, wiT_lo);

    for (int t0 = 0; t0 < T_DIM; t0 += chunk) {
        int nt = (T_DIM - t0 < chunk) ? (T_DIM - t0) : chunk;
        int rows = nt * B_DIM;
        embed_kernel<<<rows / 64, 256, 0, stream>>>(
            states + (size_t)t0 * B_DIM * S_DIMS,
            actions + (size_t)t0 * B_DIM * A_DIMS,
            rewards + (size_t)t0 * B_DIM,
            Ws, bs, Wa, ba, Wr, br, x_hi, x_lo);
        dim3 ggrid(G_DIM / 128, rows / 128);
        gates_mfma<<<ggrid, 256, 0, stream>>>(x_hi, x_lo, wiT_hi, wiT_lo, bgru, gx);
        for (int s = 0; s < nt; ++s) {
            int t = t0 + s;
            const float* hprev = (t == 0) ? nullptr : out + (size_t)(t - 1) * B_DIM * H_DIM;
            const float* gxs = gx + (size_t)s * B_DIM * G_DIM;
            gru_zr_mfma<<<dim3(16, 4), 256, 0, stream>>>(
                gxs, hprev, h_hi, h_lo, whT_hi, whT_lo, zbuf, rh_hi, rh_lo);
            gru_a_mfma<<<dim3(8, 4), 256, 0, stream>>>(
                gxs, hprev, rh_hi, rh_lo, zbuf, whT_hi, whT_lo,
                out + (size_t)t * B_DIM * H_DIM, h_hi, h_lo);
        }
    }
}

// Round 7
// 27476.917 us; speedup vs baseline: 1.0001x; 1.0001x over previous
//
#include <hip/hip_runtime.h>

#define T_DIM 512
#define B_DIM 256
#define S_DIMS 64
#define A_DIMS 16
#define E_DIM 128
#define H_DIM 512
#define X_DIM 384   // 3*E
#define G_DIM 1536  // 3*H

typedef __attribute__((ext_vector_type(8))) short short8;
typedef __attribute__((ext_vector_type(4))) float f32x4;

#define MFMA16(a, b, c) __builtin_amdgcn_mfma_f32_16x16x32_bf16(a, b, c, 0, 0, 0)

__device__ __forceinline__ float gelu_tanh(float x) {
    const float c = 0.7978845608028654f; // sqrt(2/pi)
    float x3 = x * x * x;
    return 0.5f * x * (1.0f + tanhf(c * (x + 0.044715f * x3)));
}

__device__ __forceinline__ float sigmoidf(float x) {
    return 1.0f / (1.0f + expf(-x));
}

// round-to-nearest-even fp32 -> bf16 (as ushort)
__device__ __forceinline__ unsigned short f2bf(float x) {
    unsigned u = __float_as_uint(x);
    u += 0x7FFFu + ((u >> 16) & 1u);
    return (unsigned short)(u >> 16);
}
__device__ __forceinline__ float bf2f(unsigned short b) {
    return __uint_as_float(((unsigned)b) << 16);
}

// ---------------- one-time: W[k][n] fp32 -> W^T[n][k] bf16 hi/lo
__global__ __launch_bounds__(256) void split_transpose(
    const float* __restrict__ w, int K, int N,
    unsigned short* __restrict__ t_hi, unsigned short* __restrict__ t_lo)
{
    __shared__ float tile[32][33];
    int k0 = blockIdx.x * 32, n0 = blockIdx.y * 32;
    int tid = threadIdx.x;
    #pragma unroll
    for (int p = 0; p < 4; ++p) {
        int i = tid + p * 256; int r = i >> 5, c = i & 31;
        tile[r][c] = w[(size_t)(k0 + r) * N + n0 + c];
    }
    __syncthreads();
    #pragma unroll
    for (int p = 0; p < 4; ++p) {
        int i = tid + p * 256; int r = i >> 5, c = i & 31; // r: n-local, c: k-local
        float v = tile[c][r];
        unsigned short hi = f2bf(v);
        size_t o = (size_t)(n0 + r) * K + k0 + c;
        t_hi[o] = hi;
        t_lo[o] = f2bf(v - bf2f(hi));
    }
}

// ---------------- Embedding: x = [gelu(s@Ws+bs), gelu(a@Wa+ba), gelu(r@Wr+br)]
// writes x as bf16 hi/lo, [rows][384]
__global__ __launch_bounds__(256) void embed_kernel(
    const float* __restrict__ s, const float* __restrict__ a, const float* __restrict__ r,
    const float* __restrict__ Ws, const float* __restrict__ bs,
    const float* __restrict__ Wa, const float* __restrict__ ba,
    const float* __restrict__ Wr, const float* __restrict__ br,
    unsigned short* __restrict__ x_hi, unsigned short* __restrict__ x_lo)
{
    __shared__ float Ws_s[64][128];
    __shared__ float Wa_s[16][128];
    __shared__ float Wr_s[128], bs_s[128], ba_s[128], br_s[128];
    __shared__ float s_s[64][64];
    __shared__ float a_s[64][16];
    __shared__ float r_s[64];
    int tid = threadIdx.x;
    for (int i = tid; i < 64 * 128; i += 256) Ws_s[i >> 7][i & 127] = Ws[i];
    for (int i = tid; i < 16 * 128; i += 256) Wa_s[i >> 7][i & 127] = Wa[i];
    if (tid < 128) { Wr_s[tid] = Wr[tid]; bs_s[tid] = bs[tid]; ba_s[tid] = ba[tid]; br_s[tid] = br[tid]; }
    size_t row0 = (size_t)blockIdx.x * 64;
    for (int i = tid; i < 64 * 64; i += 256) s_s[i >> 6][i & 63] = s[row0 * 64 + i];
    for (int i = tid; i < 64 * 16; i += 256) a_s[i >> 4][i & 15] = a[row0 * 16 + i];
    if (tid < 64) r_s[tid] = r[row0 + tid];
    __syncthreads();
    int e = tid & 127, ty = tid >> 7;
    for (int rw = ty; rw < 64; rw += 2) {
        float accS = bs_s[e];
        #pragma unroll
        for (int k = 0; k < 64; ++k) accS += s_s[rw][k] * Ws_s[k][e];
        float accA = ba_s[e];
        #pragma unroll
        for (int k = 0; k < 16; ++k) accA += a_s[rw][k] * Wa_s[k][e];
        float accR = br_s[e] + r_s[rw] * Wr_s[e];
        float v0 = gelu_tanh(accS);
        float v1 = gelu_tanh(accA);
        float v2 = gelu_tanh(accR);
        size_t base = (row0 + rw) * X_DIM;
        unsigned short h0 = f2bf(v0), h1 = f2bf(v1), h2 = f2bf(v2);
        x_hi[base + e] = h0;        x_lo[base + e] = f2bf(v0 - bf2f(h0));
        x_hi[base + 128 + e] = h1;  x_lo[base + 128 + e] = f2bf(v1 - bf2f(h1));
        x_hi[base + 256 + e] = h2;  x_lo[base + 256 + e] = f2bf(v2 - bf2f(h2));
    }
}

// ---------------- Gates GEMM (MFMA): gx[m][n] = x[m][:] . wiT[n][:] + bias[n]
// grid (12, rows/128): x = N-block (fastest -> A-tile L2 reuse), y = M-block.
// 256 thr = 4 waves (2M x 2N), wave-tile 64x64, 4x4 fragments.
__global__ __launch_bounds__(256) void gates_mfma(
    const unsigned short* __restrict__ x_hi, const unsigned short* __restrict__ x_lo,
    const unsigned short* __restrict__ wiT_hi, const unsigned short* __restrict__ wiT_lo,
    const float* __restrict__ bias, float* __restrict__ C)
{
    const int tid = threadIdx.x;
    const int lane = tid & 63;
    const int wv = tid >> 6;
    const int wm = wv >> 1, wn = wv & 1;
    const size_t m0 = (size_t)blockIdx.y * 128 + wm * 64;
    const int n0 = blockIdx.x * 128 + wn * 64;
    const int lr = lane & 15, lk = (lane >> 4) * 8;
    f32x4 acc[4][4] = {};
    for (int k0 = 0; k0 < X_DIM; k0 += 32) {
        short8 ahi[4], alo[4], bhi[4], blo[4];
        #pragma unroll
        for (int i = 0; i < 4; ++i) {
            size_t oa = (m0 + i * 16 + lr) * X_DIM + k0 + lk;
            ahi[i] = *reinterpret_cast<const short8*>(&x_hi[oa]);
            alo[i] = *reinterpret_cast<const short8*>(&x_lo[oa]);
            size_t ob = (size_t)(n0 + i * 16 + lr) * X_DIM + k0 + lk;
            bhi[i] = *reinterpret_cast<const short8*>(&wiT_hi[ob]);
            blo[i] = *reinterpret_cast<const short8*>(&wiT_lo[ob]);
        }
        #pragma unroll
        for (int i = 0; i < 4; ++i)
            #pragma unroll
            for (int j = 0; j < 4; ++j) {
                acc[i][j] = MFMA16(ahi[i], bhi[j], acc[i][j]);
                acc[i][j] = MFMA16(ahi[i], blo[j], acc[i][j]);
                acc[i][j] = MFMA16(alo[i], bhi[j], acc[i][j]);
            }
    }
    const int rbase = (lane >> 4) * 4;
    #pragma unroll
    for (int i = 0; i < 4; ++i)
        #pragma unroll
        for (int j = 0; j < 4; ++j) {
            int colg = n0 + j * 16 + lr;
            float b = bias[colg];
            #pragma unroll
            for (int r = 0; r < 4; ++r) {
                size_t row = m0 + i * 16 + rbase + r;
                C[row * G_DIM + colg] = acc[i][j][r] + b;
            }
        }
}

// ---------------- GRU step 1 (MFMA): zr = sigmoid(gx_zr + h @ Wzr)
// grid (16, 4): x = N-block (64 of 1024 zr-cols), y = M-block (64 of 256 rows).
// wave-tile 32x32 (2x2 fragments). Writes z (fp32) or rh = r*h (bf16 hi/lo).
__global__ __launch_bounds__(256) void gru_zr_mfma(
    const float* __restrict__ gxs,   // B x 1536
    const float* __restrict__ hprev, // B x 512 fp32 (out[t-1]) or null
    const unsigned short* __restrict__ h_hi, const unsigned short* __restrict__ h_lo,
    const unsigned short* __restrict__ whT_hi, const unsigned short* __restrict__ whT_lo, // [1536][512]
    float* __restrict__ zbuf,
    unsigned short* __restrict__ rh_hi, unsigned short* __restrict__ rh_lo)
{
    const int tid = threadIdx.x;
    const int lane = tid & 63;
    const int wv = tid >> 6;
    const int wm = wv >> 1, wn = wv & 1;
    const int m0 = blockIdx.y * 64 + wm * 32;
    const int n0 = blockIdx.x * 64 + wn * 32;   // zr col space 0..1023
    const int lr = lane & 15, lk = (lane >> 4) * 8;
    f32x4 acc[2][2] = {};
    if (hprev) {
        #pragma unroll
        for (int k0 = 0; k0 < H_DIM; k0 += 32) {
            short8 ahi[2], alo[2], bhi[2], blo[2];
            #pragma unroll
            for (int i = 0; i < 2; ++i) {
                size_t oa = (size_t)(m0 + i * 16 + lr) * H_DIM + k0 + lk;
                ahi[i] = *reinterpret_cast<const short8*>(&h_hi[oa]);
                alo[i] = *reinterpret_cast<const short8*>(&h_lo[oa]);
                size_t ob = (size_t)(n0 + i * 16 + lr) * H_DIM + k0 + lk;
                bhi[i] = *reinterpret_cast<const short8*>(&whT_hi[ob]);
                blo[i] = *reinterpret_cast<const short8*>(&whT_lo[ob]);
            }
            #pragma unroll
            for (int i = 0; i < 2; ++i)
                #pragma unroll
                for (int j = 0; j < 2; ++j) {
                    acc[i][j] = MFMA16(ahi[i], bhi[j], acc[i][j]);
                    acc[i][j] = MFMA16(ahi[i], blo[j], acc[i][j]);
                    acc[i][j] = MFMA16(alo[i], bhi[j], acc[i][j]);
                }
        }
    }
    const int rbase = (lane >> 4) * 4;
    #pragma unroll
    for (int i = 0; i < 2; ++i)
        #pragma unroll
        for (int j = 0; j < 2; ++j)
            #pragma unroll
            for (int r = 0; r < 4; ++r) {
                int row = m0 + i * 16 + rbase + r;
                int col = n0 + j * 16 + lr;
                float v = sigmoidf(gxs[(size_t)row * G_DIM + col] + acc[i][j][r]);
                if (n0 < H_DIM) {
                    zbuf[(size_t)row * H_DIM + col] = v;
                } else {
                    int c = col - H_DIM;
                    float hp = hprev ? hprev[(size_t)row * H_DIM + c] : 0.0f;
                    float rh = v * hp;
                    unsigned short hi = f2bf(rh);
                    rh_hi[(size_t)row * H_DIM + c] = hi;
                    rh_lo[(size_t)row * H_DIM + c] = f2bf(rh - bf2f(hi));
                }
            }
}

// ---------------- GRU step 2 (MFMA): a = tanh(gx_a + rh @ Wa); h = hp + z*(a-hp)
// grid (8, 4). Writes h fp32 (out) + bf16 hi/lo (next step's A operand).
__global__ __launch_bounds__(256) void gru_a_mfma(
    const float* __restrict__ gxs,   // B x 1536
    const float* __restrict__ hprev, // B x 512 fp32 or null
    const unsigned short* __restrict__ rh_hi, const unsigned short* __restrict__ rh_lo,
    const float* __restrict__ zbuf,
    const unsigned short* __restrict__ whT_hi, const unsigned short* __restrict__ whT_lo,
    float* __restrict__ hout,
    unsigned short* __restrict__ h_hi, unsigned short* __restrict__ h_lo)
{
    const int tid = threadIdx.x;
    const int lane = tid & 63;
    const int wv = tid >> 6;
    const int wm = wv >> 1, wn = wv & 1;
    const int m0 = blockIdx.y * 64 + wm * 32;
    const int n0 = blockIdx.x * 64 + wn * 32;   // a col space 0..511
    const int lr = lane & 15, lk = (lane >> 4) * 8;
    f32x4 acc[2][2] = {};
    #pragma unroll
    for (int k0 = 0; k0 < H_DIM; k0 += 32) {
        short8 ahi[2], alo[2], bhi[2], blo[2];
        #pragma unroll
        for (int i = 0; i < 2; ++i) {
            size_t oa = (size_t)(m0 + i * 16 + lr) * H_DIM + k0 + lk;
            ahi[i] = *reinterpret_cast<const short8*>(&rh_hi[oa]);
            alo[i] = *reinterpret_cast<const short8*>(&rh_lo[oa]);
            size_t ob = (size_t)(1024 + n0 + i * 16 + lr) * H_DIM + k0 + lk;
            bhi[i] = *reinterpret_cast<const short8*>(&whT_hi[ob]);
            blo[i] = *reinterpret_cast<const short8*>(&whT_lo[ob]);
        }
        #pragma unroll
        for (int i = 0; i < 2; ++i)
            #pragma unroll
            for (int j = 0; j < 2; ++j) {
                acc[i][j] = MFMA16(ahi[i], bhi[j], acc[i][j]);
                acc[i][j] = MFMA16(ahi[i], blo[j], acc[i][j]);
                acc[i][j] = MFMA16(alo[i], bhi[j], acc[i][j]);
            }
    }
    const int rbase = (lane >> 4) * 4;
    #pragma unroll
    for (int i = 0; i < 2; ++i)
        #pragma unroll
        for (int j = 0; j < 2; ++j)
            #pragma unroll
            for (int r = 0; r < 4; ++r) {
                int row = m0 + i * 16 + rbase + r;
                int col = n0 + j * 16 + lr;
                float av = tanhf(gxs[(size_t)row * G_DIM + 1024 + col] + acc[i][j][r]);
                float hp = hprev ? hprev[(size_t)row * H_DIM + col] : 0.0f;
                float z = zbuf[(size_t)row * H_DIM + col];
                float hnew = hp + z * (av - hp);
                hout[(size_t)row * H_DIM + col] = hnew;
                unsigned short hi = f2bf(hnew);
                h_hi[(size_t)row * H_DIM + col] = hi;
                h_lo[(size_t)row * H_DIM + col] = f2bf(hnew - bf2f(hi));
            }
}

extern "C" void kernel_launch(void* const* d_in, const int* in_sizes, int n_in,
                              void* d_out, int out_size, void* d_ws, size_t ws_size,
                              hipStream_t stream) {
    const float* states  = (const float*)d_in[0];
    const float* actions = (const float*)d_in[1];
    const float* rewards = (const float*)d_in[2];
    const float* Ws   = (const float*)d_in[3];
    const float* bs   = (const float*)d_in[4];
    const float* Wa   = (const float*)d_in[5];
    const float* ba   = (const float*)d_in[6];
    const float* Wr   = (const float*)d_in[7];
    const float* br   = (const float*)d_in[8];
    const float* w_i  = (const float*)d_in[9];
    const float* w_h  = (const float*)d_in[10];
    const float* bgru = (const float*)d_in[11];
    float* out = (float*)d_out;

    // ---- workspace carve-up (all region sizes multiples of 16 B)
    char* p = (char*)d_ws;
    unsigned short* whT_hi = (unsigned short*)p; p += (size_t)G_DIM * H_DIM * 2;
    unsigned short* whT_lo = (unsigned short*)p; p += (size_t)G_DIM * H_DIM * 2;
    unsigned short* wiT_hi = (unsigned short*)p; p += (size_t)G_DIM * X_DIM * 2;
    unsigned short* wiT_lo = (unsigned short*)p; p += (size_t)G_DIM * X_DIM * 2;
    float*          zbuf   = (float*)p;          p += (size_t)B_DIM * H_DIM * 4;
    unsigned short* rh_hi  = (unsigned short*)p; p += (size_t)B_DIM * H_DIM * 2;
    unsigned short* rh_lo  = (unsigned short*)p; p += (size_t)B_DIM * H_DIM * 2;
    unsigned short* h_hi   = (unsigned short*)p; p += (size_t)B_DIM * H_DIM * 2;
    unsigned short* h_lo   = (unsigned short*)p; p += (size_t)B_DIM * H_DIM * 2;
    size_t fixed = (size_t)(p - (char*)d_ws);
    size_t per_step = (size_t)B_DIM * G_DIM * 4 + (size_t)B_DIM * X_DIM * 2 * 2;
    int chunk = (int)((ws_size > fixed ? ws_size - fixed : 0) / per_step);
    if (chunk > T_DIM) chunk = T_DIM;
    if (chunk < 1) chunk = 1;
    float* gx = (float*)p;
    unsigned short* x_hi = (unsigned short*)((char*)gx + (size_t)chunk * B_DIM * G_DIM * 4);
    unsigned short* x_lo = x_hi + (size_t)chunk * B_DIM * X_DIM;

    // ---- one-time weight split/transpose
    split_transpose<<<dim3(H_DIM / 32, G_DIM / 32), 256, 0, stream>>>(w_h, H_DIM, G_DIM, whT_hi, whT_lo);
    split_transpose<<<dim3(X_DIM / 32, G_DIM / 32), 256, 0, stream>>>(w_i, X_DIM, G_DIM, wiT_hi, wiT_lo);

    for (int t0 = 0; t0 < T_DIM; t0 += chunk) {
        int nt = (T_DIM - t0 < chunk) ? (T_DIM - t0) : chunk;
        int rows = nt * B_DIM;
        embed_kernel<<<rows / 64, 256, 0, stream>>>(
            states + (size_t)t0 * B_DIM * S_DIMS,
            actions + (size_t)t0 * B_DIM * A_DIMS,
            rewards + (size_t)t0 * B_DIM,
            Ws, bs, Wa, ba, Wr, br, x_hi, x_lo);
        dim3 ggrid(G_DIM / 128, rows / 128);
        gates_mfma<<<ggrid, 256, 0, stream>>>(x_hi, x_lo, wiT_hi, wiT_lo, bgru, gx);
        for (int s = 0; s < nt; ++s) {
            int t = t0 + s;
            const float* hprev = (t == 0) ? nullptr : out + (size_t)(t - 1) * B_DIM * H_DIM;
            const float* gxs = gx + (size_t)s * B_DIM * G_DIM;
            gru_zr_mfma<<<dim3(16, 4), 256, 0, stream>>>(
                gxs, hprev, h_hi, h_lo, whT_hi, whT_lo, zbuf, rh_hi, rh_lo);
            gru_a_mfma<<<dim3(8, 4), 256, 0, stream>>>(
                gxs, hprev, rh_hi, rh_lo, zbuf, whT_hi, whT_lo,
                out + (size_t)t * B_DIM * H_DIM, h_hi, h_lo);
        }
    }
}

// Round 8
// 27465.323 us; speedup vs baseline: 1.0005x; 1.0004x over previous
//
#include <hip/hip_runtime.h>

#define T_DIM 512
#define B_DIM 256
#define S_DIMS 64
#define A_DIMS 16
#define E_DIM 128
#define H_DIM 512
#define X_DIM 384   // 3*E
#define G_DIM 1536  // 3*H

typedef __attribute__((ext_vector_type(8))) short short8;
typedef __attribute__((ext_vector_type(4))) float f32x4;

#define MFMA16(a, b, c) __builtin_amdgcn_mfma_f32_16x16x32_bf16(a, b, c, 0, 0, 0)

__device__ __forceinline__ float gelu_tanh(float x) {
    const float c = 0.7978845608028654f; // sqrt(2/pi)
    float x3 = x * x * x;
    return 0.5f * x * (1.0f + tanhf(c * (x + 0.044715f * x3)));
}

__device__ __forceinline__ float sigmoidf(float x) {
    return 1.0f / (1.0f + expf(-x));
}

// round-to-nearest-even fp32 -> bf16 (as ushort)
__device__ __forceinline__ unsigned short f2bf(float x) {
    unsigned u = __float_as_uint(x);
    u += 0x7FFFu + ((u >> 16) & 1u);
    return (unsigned short)(u >> 16);
}
__device__ __forceinline__ float bf2f(unsigned short b) {
    return __uint_as_float(((unsigned)b) << 16);
}

// ---------------- one-time: W[k][n] fp32 -> W^T[n][k] bf16 hi/lo
__global__ __launch_bounds__(256) void split_transpose(
    const float* __restrict__ w, int K, int N,
    unsigned short* __restrict__ t_hi, unsigned short* __restrict__ t_lo)
{
    __shared__ float tile[32][33];
    int k0 = blockIdx.x * 32, n0 = blockIdx.y * 32;
    int tid = threadIdx.x;
    #pragma unroll
    for (int p = 0; p < 4; ++p) {
        int i = tid + p * 256; int r = i >> 5, c = i & 31;
        tile[r][c] = w[(size_t)(k0 + r) * N + n0 + c];
    }
    __syncthreads();
    #pragma unroll
    for (int p = 0; p < 4; ++p) {
        int i = tid + p * 256; int r = i >> 5, c = i & 31; // r: n-local, c: k-local
        float v = tile[c][r];
        unsigned short hi = f2bf(v);
        size_t o = (size_t)(n0 + r) * K + k0 + c;
        t_hi[o] = hi;
        t_lo[o] = f2bf(v - bf2f(hi));
    }
}

// ---------------- Embedding: x = [gelu(s@Ws+bs), gelu(a@Wa+ba), gelu(r@Wr+br)]
// writes x as bf16 hi/lo, [rows][384]
__global__ __launch_bounds__(256) void embed_kernel(
    const float* __restrict__ s, const float* __restrict__ a, const float* __restrict__ r,
    const float* __restrict__ Ws, const float* __restrict__ bs,
    const float* __restrict__ Wa, const float* __restrict__ ba,
    const float* __restrict__ Wr, const float* __restrict__ br,
    unsigned short* __restrict__ x_hi, unsigned short* __restrict__ x_lo)
{
    __shared__ float Ws_s[64][128];
    __shared__ float Wa_s[16][128];
    __shared__ float Wr_s[128], bs_s[128], ba_s[128], br_s[128];
    __shared__ float s_s[64][64];
    __shared__ float a_s[64][16];
    __shared__ float r_s[64];
    int tid = threadIdx.x;
    for (int i = tid; i < 64 * 128; i += 256) Ws_s[i >> 7][i & 127] = Ws[i];
    for (int i = tid; i < 16 * 128; i += 256) Wa_s[i >> 7][i & 127] = Wa[i];
    if (tid < 128) { Wr_s[tid] = Wr[tid]; bs_s[tid] = bs[tid]; ba_s[tid] = ba[tid]; br_s[tid] = br[tid]; }
    size_t row0 = (size_t)blockIdx.x * 64;
    for (int i = tid; i < 64 * 64; i += 256) s_s[i >> 6][i & 63] = s[row0 * 64 + i];
    for (int i = tid; i < 64 * 16; i += 256) a_s[i >> 4][i & 15] = a[row0 * 16 + i];
    if (tid < 64) r_s[tid] = r[row0 + tid];
    __syncthreads();
    int e = tid & 127, ty = tid >> 7;
    for (int rw = ty; rw < 64; rw += 2) {
        float accS = bs_s[e];
        #pragma unroll
        for (int k = 0; k < 64; ++k) accS += s_s[rw][k] * Ws_s[k][e];
        float accA = ba_s[e];
        #pragma unroll
        for (int k = 0; k < 16; ++k) accA += a_s[rw][k] * Wa_s[k][e];
        float accR = br_s[e] + r_s[rw] * Wr_s[e];
        float v0 = gelu_tanh(accS);
        float v1 = gelu_tanh(accA);
        float v2 = gelu_tanh(accR);
        size_t base = (row0 + rw) * X_DIM;
        unsigned short h0 = f2bf(v0), h1 = f2bf(v1), h2 = f2bf(v2);
        x_hi[base + e] = h0;        x_lo[base + e] = f2bf(v0 - bf2f(h0));
        x_hi[base + 128 + e] = h1;  x_lo[base + 128 + e] = f2bf(v1 - bf2f(h1));
        x_hi[base + 256 + e] = h2;  x_lo[base + 256 + e] = f2bf(v2 - bf2f(h2));
    }
}

// ---------------- Gates GEMM (MFMA): gx[m][n] = x[m][:] . wiT[n][:] + bias[n]
// grid (12, rows/128): x = N-block (fastest -> A-tile L2 reuse), y = M-block.
// 256 thr = 4 waves (2M x 2N), wave-tile 64x64, 4x4 fragments.
__global__ __launch_bounds__(256) void gates_mfma(
    const unsigned short* __restrict__ x_hi, const unsigned short* __restrict__ x_lo,
    const unsigned short* __restrict__ wiT_hi, const unsigned short* __restrict__ wiT_lo,
    const float* __restrict__ bias, float* __restrict__ C)
{
    const int tid = threadIdx.x;
    const int lane = tid & 63;
    const int wv = tid >> 6;
    const int wm = wv >> 1, wn = wv & 1;
    const size_t m0 = (size_t)blockIdx.y * 128 + wm * 64;
    const int n0 = blockIdx.x * 128 + wn * 64;
    const int lr = lane & 15, lk = (lane >> 4) * 8;
    f32x4 acc[4][4] = {};
    for (int k0 = 0; k0 < X_DIM; k0 += 32) {
        short8 ahi[4], alo[4], bhi[4], blo[4];
        #pragma unroll
        for (int i = 0; i < 4; ++i) {
            size_t oa = (m0 + i * 16 + lr) * X_DIM + k0 + lk;
            ahi[i] = *reinterpret_cast<const short8*>(&x_hi[oa]);
            alo[i] = *reinterpret_cast<const short8*>(&x_lo[oa]);
            size_t ob = (size_t)(n0 + i * 16 + lr) * X_DIM + k0 + lk;
            bhi[i] = *reinterpret_cast<const short8*>(&wiT_hi[ob]);
            blo[i] = *reinterpret_cast<const short8*>(&wiT_lo[ob]);
        }
        #pragma unroll
        for (int i = 0; i < 4; ++i)
            #pragma unroll
            for (int j = 0; j < 4; ++j) {
                acc[i][j] = MFMA16(ahi[i], bhi[j], acc[i][j]);
                acc[i][j] = MFMA16(ahi[i], blo[j], acc[i][j]);
                acc[i][j] = MFMA16(alo[i], bhi[j], acc[i][j]);
            }
    }
    const int rbase = (lane >> 4) * 4;
    #pragma unroll
    for (int i = 0; i < 4; ++i)
        #pragma unroll
        for (int j = 0; j < 4; ++j) {
            int colg = n0 + j * 16 + lr;
            float b = bias[colg];
            #pragma unroll
            for (int r = 0; r < 4; ++r) {
                size_t row = m0 + i * 16 + rbase + r;
                C[row * G_DIM + colg] = acc[i][j][r] + b;
            }
        }
}

// ---------------- GRU step 1 (MFMA): zr = sigmoid(gx_zr + h @ Wzr)
// grid (16, 4): x = N-block (64 of 1024 zr-cols), y = M-block (64 of 256 rows).
// wave-tile 32x32 (2x2 fragments). Writes z (fp32) or rh = r*h (bf16 hi/lo).
__global__ __launch_bounds__(256) void gru_zr_mfma(
    const float* __restrict__ gxs,   // B x 1536
    const float* __restrict__ hprev, // B x 512 fp32 (out[t-1]) or null
    const unsigned short* __restrict__ h_hi, const unsigned short* __restrict__ h_lo,
    const unsigned short* __restrict__ whT_hi, const unsigned short* __restrict__ whT_lo, // [1536][512]
    float* __restrict__ zbuf,
    unsigned short* __restrict__ rh_hi, unsigned short* __restrict__ rh_lo)
{
    const int tid = threadIdx.x;
    const int lane = tid & 63;
    const int wv = tid >> 6;
    const int wm = wv >> 1, wn = wv & 1;
    const int m0 = blockIdx.y * 64 + wm * 32;
    const int n0 = blockIdx.x * 64 + wn * 32;   // zr col space 0..1023
    const int lr = lane & 15, lk = (lane >> 4) * 8;
    f32x4 acc[2][2] = {};
    if (hprev) {
        #pragma unroll
        for (int k0 = 0; k0 < H_DIM; k0 += 32) {
            short8 ahi[2], alo[2], bhi[2], blo[2];
            #pragma unroll
            for (int i = 0; i < 2; ++i) {
                size_t oa = (size_t)(m0 + i * 16 + lr) * H_DIM + k0 + lk;
                ahi[i] = *reinterpret_cast<const short8*>(&h_hi[oa]);
                alo[i] = *reinterpret_cast<const short8*>(&h_lo[oa]);
                size_t ob = (size_t)(n0 + i * 16 + lr) * H_DIM + k0 + lk;
                bhi[i] = *reinterpret_cast<const short8*>(&whT_hi[ob]);
                blo[i] = *reinterpret_cast<const short8*>(&whT_lo[ob]);
            }
            #pragma unroll
            for (int i = 0; i < 2; ++i)
                #pragma unroll
                for (int j = 0; j < 2; ++j) {
                    acc[i][j] = MFMA16(ahi[i], bhi[j], acc[i][j]);
                    acc[i][j] = MFMA16(ahi[i], blo[j], acc[i][j]);
                    acc[i][j] = MFMA16(alo[i], bhi[j], acc[i][j]);
                }
        }
    }
    const int rbase = (lane >> 4) * 4;
    #pragma unroll
    for (int i = 0; i < 2; ++i)
        #pragma unroll
        for (int j = 0; j < 2; ++j)
            #pragma unroll
            for (int r = 0; r < 4; ++r) {
                int row = m0 + i * 16 + rbase + r;
                int col = n0 + j * 16 + lr;
                float v = sigmoidf(gxs[(size_t)row * G_DIM + col] + acc[i][j][r]);
                if (n0 < H_DIM) {
                    zbuf[(size_t)row * H_DIM + col] = v;
                } else {
                    int c = col - H_DIM;
                    float hp = hprev ? hprev[(size_t)row * H_DIM + c] : 0.0f;
                    float rh = v * hp;
                    unsigned short hi = f2bf(rh);
                    rh_hi[(size_t)row * H_DIM + c] = hi;
                    rh_lo[(size_t)row * H_DIM + c] = f2bf(rh - bf2f(hi));
                }
            }
}

// ---------------- GRU step 2 (MFMA): a = tanh(gx_a + rh @ Wa); h = hp + z*(a-hp)
// grid (8, 4). Writes h fp32 (out) + bf16 hi/lo (next step's A operand).
__global__ __launch_bounds__(256) void gru_a_mfma(
    const float* __restrict__ gxs,   // B x 1536
    const float* __restrict__ hprev, // B x 512 fp32 or null
    const unsigned short* __restrict__ rh_hi, const unsigned short* __restrict__ rh_lo,
    const float* __restrict__ zbuf,
    const unsigned short* __restrict__ whT_hi, const unsigned short* __restrict__ whT_lo,
    float* __restrict__ hout,
    unsigned short* __restrict__ h_hi, unsigned short* __restrict__ h_lo)
{
    const int tid = threadIdx.x;
    const int lane = tid & 63;
    const int wv = tid >> 6;
    const int wm = wv >> 1, wn = wv & 1;
    const int m0 = blockIdx.y * 64 + wm * 32;
    const int n0 = blockIdx.x * 64 + wn * 32;   // a col space 0..511
    const int lr = lane & 15, lk = (lane >> 4) * 8;
    f32x4 acc[2][2] = {};
    #pragma unroll
    for (int k0 = 0; k0 < H_DIM; k0 += 32) {
        short8 ahi[2], alo[2], bhi[2], blo[2];
        #pragma unroll
        for (int i = 0; i < 2; ++i) {
            size_t oa = (size_t)(m0 + i * 16 + lr) * H_DIM + k0 + lk;
            ahi[i] = *reinterpret_cast<const short8*>(&rh_hi[oa]);
            alo[i] = *reinterpret_cast<const short8*>(&rh_lo[oa]);
            size_t ob = (size_t)(1024 + n0 + i * 16 + lr) * H_DIM + k0 + lk;
            bhi[i] = *reinterpret_cast<const short8*>(&whT_hi[ob]);
            blo[i] = *reinterpret_cast<const short8*>(&whT_lo[ob]);
        }
        #pragma unroll
        for (int i = 0; i < 2; ++i)
            #pragma unroll
            for (int j = 0; j < 2; ++j) {
                acc[i][j] = MFMA16(ahi[i], bhi[j], acc[i][j]);
                acc[i][j] = MFMA16(ahi[i], blo[j], acc[i][j]);
                acc[i][j] = MFMA16(alo[i], bhi[j], acc[i][j]);
            }
    }
    const int rbase = (lane >> 4) * 4;
    #pragma unroll
    for (int i = 0; i < 2; ++i)
        #pragma unroll
        for (int j = 0; j < 2; ++j)
            #pragma unroll
            for (int r = 0; r < 4; ++r) {
                int row = m0 + i * 16 + rbase + r;
                int col = n0 + j * 16 + lr;
                float av = tanhf(gxs[(size_t)row * G_DIM + 1024 + col] + acc[i][j][r]);
                float hp = hprev ? hprev[(size_t)row * H_DIM + col] : 0.0f;
                float z = zbuf[(size_t)row * H_DIM + col];
                float hnew = hp + z * (av - hp);
                hout[(size_t)row * H_DIM + col] = hnew;
                unsigned short hi = f2bf(hnew);
                h_hi[(size_t)row * H_DIM + col] = hi;
                h_lo[(size_t)row * H_DIM + col] = f2bf(hnew - bf2f(hi));
            }
}

extern "C" void kernel_launch(void* const* d_in, const int* in_sizes, int n_in,
                              void* d_out, int out_size, void* d_ws, size_t ws_size,
                              hipStream_t stream) {
    const float* states  = (const float*)d_in[0];
    const float* actions = (const float*)d_in[1];
    const float* rewards = (const float*)d_in[2];
    const float* Ws   = (const float*)d_in[3];
    const float* bs   = (const float*)d_in[4];
    const float* Wa   = (const float*)d_in[5];
    const float* ba   = (const float*)d_in[6];
    const float* Wr   = (const float*)d_in[7];
    const float* br   = (const float*)d_in[8];
    const float* w_i  = (const float*)d_in[9];
    const float* w_h  = (const float*)d_in[10];
    const float* bgru = (const float*)d_in[11];
    float* out = (float*)d_out;

    // ---- workspace carve-up (all region sizes multiples of 16 B)
    char* p = (char*)d_ws;
    unsigned short* whT_hi = (unsigned short*)p; p += (size_t)G_DIM * H_DIM * 2;
    unsigned short* whT_lo = (unsigned short*)p; p += (size_t)G_DIM * H_DIM * 2;
    unsigned short* wiT_hi = (unsigned short*)p; p += (size_t)G_DIM * X_DIM * 2;
    unsigned short* wiT_lo = (unsigned short*)p; p += (size_t)G_DIM * X_DIM * 2;
    float*          zbuf   = (float*)p;          p += (size_t)B_DIM * H_DIM * 4;
    unsigned short* rh_hi  = (unsigned short*)p; p += (size_t)B_DIM * H_DIM * 2;
    unsigned short* rh_lo  = (unsigned short*)p; p += (size_t)B_DIM * H_DIM * 2;
    unsigned short* h_hi   = (unsigned short*)p; p += (size_t)B_DIM * H_DIM * 2;
    unsigned short* h_lo   = (unsigned short*)p; p += (size_t)B_DIM * H_DIM * 2;
    size_t fixed = (size_t)(p - (char*)d_ws);
    size_t per_step = (size_t)B_DIM * G_DIM * 4 + (size_t)B_DIM * X_DIM * 2 * 2;
    int chunk = (int)((ws_size > fixed ? ws_size - fixed : 0) / per_step);
    if (chunk > T_DIM) chunk = T_DIM;
    if (chunk < 1) chunk = 1;
    float* gx = (float*)p;
    unsigned short* x_hi = (unsigned short*)((char*)gx + (size_t)chunk * B_DIM * G_DIM * 4);
    unsigned short* x_lo = x_hi + (size_t)chunk * B_DIM * X_DIM;

    // ---- one-time weight split/transpose
    split_transpose<<<dim3(H_DIM / 32, G_DIM / 32), 256, 0, stream>>>(w_h, H_DIM, G_DIM, whT_hi, whT_lo);
    split_transpose<<<dim3(X_DIM / 32, G_DIM / 32), 256, 0, stream>>>(w_i, X_DIM, G_DIM, wiT_hi, wiT_lo);

    for (int t0 = 0; t0 < T_DIM; t0 += chunk) {
        int nt = (T_DIM - t0 < chunk) ? (T_DIM - t0) : chunk;
        int rows = nt * B_DIM;
        embed_kernel<<<rows / 64, 256, 0, stream>>>(
            states + (size_t)t0 * B_DIM * S_DIMS,
            actions + (size_t)t0 * B_DIM * A_DIMS,
            rewards + (size_t)t0 * B_DIM,
            Ws, bs, Wa, ba, Wr, br, x_hi, x_lo);
        dim3 ggrid(G_DIM / 128, rows / 128);
        gates_mfma<<<ggrid, 256, 0, stream>>>(x_hi, x_lo, wiT_hi, wiT_lo, bgru, gx);
        for (int s = 0; s < nt; ++s) {
            int t = t0 + s;
            const float* hprev = (t == 0) ? nullptr : out + (size_t)(t - 1) * B_DIM * H_DIM;
            const float* gxs = gx + (size_t)s * B_DIM * G_DIM;
            gru_zr_mfma<<<dim3(16, 4), 256, 0, stream>>>(
                gxs, hprev, h_hi, h_lo, whT_hi, whT_lo, zbuf, rh_hi, rh_lo);
            gru_a_mfma<<<dim3(8, 4), 256, 0, stream>>>(
                gxs, hprev, rh_hi, rh_lo, zbuf, whT_hi, whT_lo,
                out + (size_t)t * B_DIM * H_DIM, h_hi, h_lo);
        }
    }
}

// Round 9
// 13900.580 us; speedup vs baseline: 1.9768x; 1.9758x over previous
//
#include <hip/hip_runtime.h>

#define T_DIM 512
#define B_DIM 256
#define S_DIMS 64
#define A_DIMS 16
#define E_DIM 128
#define H_DIM 512
#define X_DIM 384   // 3*E
#define G_DIM 1536  // 3*H

typedef __attribute__((ext_vector_type(8))) short short8;
typedef __attribute__((ext_vector_type(4))) float f32x4;

#define MFMA16(a, b, c) __builtin_amdgcn_mfma_f32_16x16x32_bf16(a, b, c, 0, 0, 0)

__device__ __forceinline__ float gelu_tanh(float x) {
    const float c = 0.7978845608028654f; // sqrt(2/pi)
    float x3 = x * x * x;
    return 0.5f * x * (1.0f + tanhf(c * (x + 0.044715f * x3)));
}

__device__ __forceinline__ float sigmoidf(float x) {
    return 1.0f / (1.0f + expf(-x));
}

// round-to-nearest-even fp32 -> bf16 (as ushort)
__device__ __forceinline__ unsigned short f2bf(float x) {
    unsigned u = __float_as_uint(x);
    u += 0x7FFFu + ((u >> 16) & 1u);
    return (unsigned short)(u >> 16);
}
__device__ __forceinline__ float bf2f(unsigned short b) {
    return __uint_as_float(((unsigned)b) << 16);
}

// ---------------- one-time: W[k][n] fp32 -> W^T[n][k] bf16 hi/lo
__global__ __launch_bounds__(256) void split_transpose(
    const float* __restrict__ w, int K, int N,
    unsigned short* __restrict__ t_hi, unsigned short* __restrict__ t_lo)
{
    __shared__ float tile[32][33];
    int k0 = blockIdx.x * 32, n0 = blockIdx.y * 32;
    int tid = threadIdx.x;
    #pragma unroll
    for (int p = 0; p < 4; ++p) {
        int i = tid + p * 256; int r = i >> 5, c = i & 31;
        tile[r][c] = w[(size_t)(k0 + r) * N + n0 + c];
    }
    __syncthreads();
    #pragma unroll
    for (int p = 0; p < 4; ++p) {
        int i = tid + p * 256; int r = i >> 5, c = i & 31; // r: n-local, c: k-local
        float v = tile[c][r];
        unsigned short hi = f2bf(v);
        size_t o = (size_t)(n0 + r) * K + k0 + c;
        t_hi[o] = hi;
        t_lo[o] = f2bf(v - bf2f(hi));
    }
}

// ---------------- Embedding: x = [gelu(s@Ws+bs), gelu(a@Wa+ba), gelu(r@Wr+br)]
// writes x as bf16 hi/lo, [rows][384]
__global__ __launch_bounds__(256) void embed_kernel(
    const float* __restrict__ s, const float* __restrict__ a, const float* __restrict__ r,
    const float* __restrict__ Ws, const float* __restrict__ bs,
    const float* __restrict__ Wa, const float* __restrict__ ba,
    const float* __restrict__ Wr, const float* __restrict__ br,
    unsigned short* __restrict__ x_hi, unsigned short* __restrict__ x_lo)
{
    __shared__ float Ws_s[64][128];
    __shared__ float Wa_s[16][128];
    __shared__ float Wr_s[128], bs_s[128], ba_s[128], br_s[128];
    __shared__ float s_s[64][64];
    __shared__ float a_s[64][16];
    __shared__ float r_s[64];
    int tid = threadIdx.x;
    for (int i = tid; i < 64 * 128; i += 256) Ws_s[i >> 7][i & 127] = Ws[i];
    for (int i = tid; i < 16 * 128; i += 256) Wa_s[i >> 7][i & 127] = Wa[i];
    if (tid < 128) { Wr_s[tid] = Wr[tid]; bs_s[tid] = bs[tid]; ba_s[tid] = ba[tid]; br_s[tid] = br[tid]; }
    size_t row0 = (size_t)blockIdx.x * 64;
    for (int i = tid; i < 64 * 64; i += 256) s_s[i >> 6][i & 63] = s[row0 * 64 + i];
    for (int i = tid; i < 64 * 16; i += 256) a_s[i >> 4][i & 15] = a[row0 * 16 + i];
    if (tid < 64) r_s[tid] = r[row0 + tid];
    __syncthreads();
    int e = tid & 127, ty = tid >> 7;
    for (int rw = ty; rw < 64; rw += 2) {
        float accS = bs_s[e];
        #pragma unroll
        for (int k = 0; k < 64; ++k) accS += s_s[rw][k] * Ws_s[k][e];
        float accA = ba_s[e];
        #pragma unroll
        for (int k = 0; k < 16; ++k) accA += a_s[rw][k] * Wa_s[k][e];
        float accR = br_s[e] + r_s[rw] * Wr_s[e];
        float v0 = gelu_tanh(accS);
        float v1 = gelu_tanh(accA);
        float v2 = gelu_tanh(accR);
        size_t base = (row0 + rw) * X_DIM;
        unsigned short h0 = f2bf(v0), h1 = f2bf(v1), h2 = f2bf(v2);
        x_hi[base + e] = h0;        x_lo[base + e] = f2bf(v0 - bf2f(h0));
        x_hi[base + 128 + e] = h1;  x_lo[base + 128 + e] = f2bf(v1 - bf2f(h1));
        x_hi[base + 256 + e] = h2;  x_lo[base + 256 + e] = f2bf(v2 - bf2f(h2));
    }
}

// ---------------- Gates GEMM (MFMA): gx[m][n] = x[m][:] . wiT[n][:] + bias[n]
// grid (12, rows/128): x = N-block (fastest -> A-tile L2 reuse), y = M-block.
// 256 thr = 4 waves (2M x 2N), wave-tile 64x64, 4x4 fragments.
__global__ __launch_bounds__(256) void gates_mfma(
    const unsigned short* __restrict__ x_hi, const unsigned short* __restrict__ x_lo,
    const unsigned short* __restrict__ wiT_hi, const unsigned short* __restrict__ wiT_lo,
    const float* __restrict__ bias, float* __restrict__ C)
{
    const int tid = threadIdx.x;
    const int lane = tid & 63;
    const int wv = tid >> 6;
    const int wm = wv >> 1, wn = wv & 1;
    const size_t m0 = (size_t)blockIdx.y * 128 + wm * 64;
    const int n0 = blockIdx.x * 128 + wn * 64;
    const int lr = lane & 15, lk = (lane >> 4) * 8;
    f32x4 acc[4][4] = {};
    for (int k0 = 0; k0 < X_DIM; k0 += 32) {
        short8 ahi[4], alo[4], bhi[4], blo[4];
        #pragma unroll
        for (int i = 0; i < 4; ++i) {
            size_t oa = (m0 + i * 16 + lr) * X_DIM + k0 + lk;
            ahi[i] = *reinterpret_cast<const short8*>(&x_hi[oa]);
            alo[i] = *reinterpret_cast<const short8*>(&x_lo[oa]);
            size_t ob = (size_t)(n0 + i * 16 + lr) * X_DIM + k0 + lk;
            bhi[i] = *reinterpret_cast<const short8*>(&wiT_hi[ob]);
            blo[i] = *reinterpret_cast<const short8*>(&wiT_lo[ob]);
        }
        #pragma unroll
        for (int i = 0; i < 4; ++i)
            #pragma unroll
            for (int j = 0; j < 4; ++j) {
                acc[i][j] = MFMA16(ahi[i], bhi[j], acc[i][j]);
                acc[i][j] = MFMA16(ahi[i], blo[j], acc[i][j]);
                acc[i][j] = MFMA16(alo[i], bhi[j], acc[i][j]);
            }
    }
    const int rbase = (lane >> 4) * 4;
    #pragma unroll
    for (int i = 0; i < 4; ++i)
        #pragma unroll
        for (int j = 0; j < 4; ++j) {
            int colg = n0 + j * 16 + lr;
            float b = bias[colg];
            #pragma unroll
            for (int r = 0; r < 4; ++r) {
                size_t row = m0 + i * 16 + rbase + r;
                C[row * G_DIM + colg] = acc[i][j][r] + b;
            }
        }
}

// ---------------- GRU step 1 (MFMA): zr = sigmoid(gx_zr + h @ Wzr)
// grid (32, 8) = 256 blocks; block = 4 waves (2M x 2N), wave-tile 16x16.
// Depth-1 register prefetch on K; no LDS. Writes z (fp32) / rh (bf16 hi/lo).
__global__ __launch_bounds__(256) void gru_zr_mfma(
    const float* __restrict__ gxs,   // B x 1536
    const float* __restrict__ hprev, // B x 512 fp32 (out[t-1]) or null
    const unsigned short* __restrict__ h_hi, const unsigned short* __restrict__ h_lo,
    const unsigned short* __restrict__ whT_hi, const unsigned short* __restrict__ whT_lo, // [1536][512]
    float* __restrict__ zbuf,
    unsigned short* __restrict__ rh_hi, unsigned short* __restrict__ rh_lo)
{
    const int tid = threadIdx.x;
    const int lane = tid & 63;
    const int wv = tid >> 6;
    const int wm = wv >> 1, wn = wv & 1;
    const int m0 = blockIdx.y * 32 + wm * 16;
    const int n0 = blockIdx.x * 32 + wn * 16;   // zr col space 0..1023
    const int lr = lane & 15, lk = (lane >> 4) * 8;
    f32x4 acc = {};
    if (hprev) {
        const unsigned short* pa_hi = h_hi  + (size_t)(m0 + lr) * H_DIM + lk;
        const unsigned short* pa_lo = h_lo  + (size_t)(m0 + lr) * H_DIM + lk;
        const unsigned short* pb_hi = whT_hi + (size_t)(n0 + lr) * H_DIM + lk;
        const unsigned short* pb_lo = whT_lo + (size_t)(n0 + lr) * H_DIM + lk;
        short8 ah = *reinterpret_cast<const short8*>(pa_hi);
        short8 al = *reinterpret_cast<const short8*>(pa_lo);
        short8 bh = *reinterpret_cast<const short8*>(pb_hi);
        short8 bl = *reinterpret_cast<const short8*>(pb_lo);
        for (int k0 = 0; k0 < H_DIM; k0 += 32) {
            short8 ah2 = ah, al2 = al, bh2 = bh, bl2 = bl;
            if (k0 + 32 < H_DIM) {
                ah2 = *reinterpret_cast<const short8*>(pa_hi + k0 + 32);
                al2 = *reinterpret_cast<const short8*>(pa_lo + k0 + 32);
                bh2 = *reinterpret_cast<const short8*>(pb_hi + k0 + 32);
                bl2 = *reinterpret_cast<const short8*>(pb_lo + k0 + 32);
            }
            acc = MFMA16(ah, bh, acc);
            acc = MFMA16(ah, bl, acc);
            acc = MFMA16(al, bh, acc);
            ah = ah2; al = al2; bh = bh2; bl = bl2;
        }
    }
    const int rbase = (lane >> 4) * 4;
    const int col = n0 + lr;
    #pragma unroll
    for (int r = 0; r < 4; ++r) {
        int row = m0 + rbase + r;
        float v = sigmoidf(gxs[(size_t)row * G_DIM + col] + acc[r]);
        if (n0 < H_DIM) {
            zbuf[(size_t)row * H_DIM + col] = v;
        } else {
            int c = col - H_DIM;
            float hp = hprev ? hprev[(size_t)row * H_DIM + c] : 0.0f;
            float rh = v * hp;
            unsigned short hi = f2bf(rh);
            rh_hi[(size_t)row * H_DIM + c] = hi;
            rh_lo[(size_t)row * H_DIM + c] = f2bf(rh - bf2f(hi));
        }
    }
}

// ---------------- GRU step 2 (MFMA): a = tanh(gx_a + rh @ Wa); h = hp + z*(a-hp)
// grid (16, 8) = 128 blocks; block = 4 waves (2M x 2N), wave-tile 16x16.
// Writes h fp32 (out) + bf16 hi/lo (next step's A operand).
__global__ __launch_bounds__(256) void gru_a_mfma(
    const float* __restrict__ gxs,   // B x 1536
    const float* __restrict__ hprev, // B x 512 fp32 or null
    const unsigned short* __restrict__ rh_hi, const unsigned short* __restrict__ rh_lo,
    const float* __restrict__ zbuf,
    const unsigned short* __restrict__ whT_hi, const unsigned short* __restrict__ whT_lo,
    float* __restrict__ hout,
    unsigned short* __restrict__ h_hi, unsigned short* __restrict__ h_lo)
{
    const int tid = threadIdx.x;
    const int lane = tid & 63;
    const int wv = tid >> 6;
    const int wm = wv >> 1, wn = wv & 1;
    const int m0 = blockIdx.y * 32 + wm * 16;
    const int n0 = blockIdx.x * 32 + wn * 16;   // a col space 0..511
    const int lr = lane & 15, lk = (lane >> 4) * 8;
    f32x4 acc = {};
    {
        const unsigned short* pa_hi = rh_hi + (size_t)(m0 + lr) * H_DIM + lk;
        const unsigned short* pa_lo = rh_lo + (size_t)(m0 + lr) * H_DIM + lk;
        const unsigned short* pb_hi = whT_hi + (size_t)(1024 + n0 + lr) * H_DIM + lk;
        const unsigned short* pb_lo = whT_lo + (size_t)(1024 + n0 + lr) * H_DIM + lk;
        short8 ah = *reinterpret_cast<const short8*>(pa_hi);
        short8 al = *reinterpret_cast<const short8*>(pa_lo);
        short8 bh = *reinterpret_cast<const short8*>(pb_hi);
        short8 bl = *reinterpret_cast<const short8*>(pb_lo);
        for (int k0 = 0; k0 < H_DIM; k0 += 32) {
            short8 ah2 = ah, al2 = al, bh2 = bh, bl2 = bl;
            if (k0 + 32 < H_DIM) {
                ah2 = *reinterpret_cast<const short8*>(pa_hi + k0 + 32);
                al2 = *reinterpret_cast<const short8*>(pa_lo + k0 + 32);
                bh2 = *reinterpret_cast<const short8*>(pb_hi + k0 + 32);
                bl2 = *reinterpret_cast<const short8*>(pb_lo + k0 + 32);
            }
            acc = MFMA16(ah, bh, acc);
            acc = MFMA16(ah, bl, acc);
            acc = MFMA16(al, bh, acc);
            ah = ah2; al = al2; bh = bh2; bl = bl2;
        }
    }
    const int rbase = (lane >> 4) * 4;
    const int col = n0 + lr;
    #pragma unroll
    for (int r = 0; r < 4; ++r) {
        int row = m0 + rbase + r;
        float av = tanhf(gxs[(size_t)row * G_DIM + 1024 + col] + acc[r]);
        float hp = hprev ? hprev[(size_t)row * H_DIM + col] : 0.0f;
        float z = zbuf[(size_t)row * H_DIM + col];
        float hnew = hp + z * (av - hp);
        hout[(size_t)row * H_DIM + col] = hnew;
        unsigned short hi = f2bf(hnew);
        h_hi[(size_t)row * H_DIM + col] = hi;
        h_lo[(size_t)row * H_DIM + col] = f2bf(hnew - bf2f(hi));
    }
}

extern "C" void kernel_launch(void* const* d_in, const int* in_sizes, int n_in,
                              void* d_out, int out_size, void* d_ws, size_t ws_size,
                              hipStream_t stream) {
    const float* states  = (const float*)d_in[0];
    const float* actions = (const float*)d_in[1];
    const float* rewards = (const float*)d_in[2];
    const float* Ws   = (const float*)d_in[3];
    const float* bs   = (const float*)d_in[4];
    const float* Wa   = (const float*)d_in[5];
    const float* ba   = (const float*)d_in[6];
    const float* Wr   = (const float*)d_in[7];
    const float* br   = (const float*)d_in[8];
    const float* w_i  = (const float*)d_in[9];
    const float* w_h  = (const float*)d_in[10];
    const float* bgru = (const float*)d_in[11];
    float* out = (float*)d_out;

    // ---- workspace carve-up (all region sizes multiples of 16 B)
    char* p = (char*)d_ws;
    unsigned short* whT_hi = (unsigned short*)p; p += (size_t)G_DIM * H_DIM * 2;
    unsigned short* whT_lo = (unsigned short*)p; p += (size_t)G_DIM * H_DIM * 2;
    unsigned short* wiT_hi = (unsigned short*)p; p += (size_t)G_DIM * X_DIM * 2;
    unsigned short* wiT_lo = (unsigned short*)p; p += (size_t)G_DIM * X_DIM * 2;
    float*          zbuf   = (float*)p;          p += (size_t)B_DIM * H_DIM * 4;
    unsigned short* rh_hi  = (unsigned short*)p; p += (size_t)B_DIM * H_DIM * 2;
    unsigned short* rh_lo  = (unsigned short*)p; p += (size_t)B_DIM * H_DIM * 2;
    unsigned short* h_hi   = (unsigned short*)p; p += (size_t)B_DIM * H_DIM * 2;
    unsigned short* h_lo   = (unsigned short*)p; p += (size_t)B_DIM * H_DIM * 2;
    size_t fixed = (size_t)(p - (char*)d_ws);
    size_t per_step = (size_t)B_DIM * G_DIM * 4 + (size_t)B_DIM * X_DIM * 2 * 2;
    int chunk = (int)((ws_size > fixed ? ws_size - fixed : 0) / per_step);
    if (chunk > T_DIM) chunk = T_DIM;
    if (chunk < 1) chunk = 1;
    float* gx = (float*)p;
    unsigned short* x_hi = (unsigned short*)((char*)gx + (size_t)chunk * B_DIM * G_DIM * 4);
    unsigned short* x_lo = x_hi + (size_t)chunk * B_DIM * X_DIM;

    // ---- one-time weight split/transpose
    split_transpose<<<dim3(H_DIM / 32, G_DIM / 32), 256, 0, stream>>>(w_h, H_DIM, G_DIM, whT_hi, whT_lo);
    split_transpose<<<dim3(X_DIM / 32, G_DIM / 32), 256, 0, stream>>>(w_i, X_DIM, G_DIM, wiT_hi, wiT_lo);

    for (int t0 = 0; t0 < T_DIM; t0 += chunk) {
        int nt = (T_DIM - t0 < chunk) ? (T_DIM - t0) : chunk;
        int rows = nt * B_DIM;
        embed_kernel<<<rows / 64, 256, 0, stream>>>(
            states + (size_t)t0 * B_DIM * S_DIMS,
            actions + (size_t)t0 * B_DIM * A_DIMS,
            rewards + (size_t)t0 * B_DIM,
            Ws, bs, Wa, ba, Wr, br, x_hi, x_lo);
        dim3 ggrid(G_DIM / 128, rows / 128);
        gates_mfma<<<ggrid, 256, 0, stream>>>(x_hi, x_lo, wiT_hi, wiT_lo, bgru, gx);
        for (int s = 0; s < nt; ++s) {
            int t = t0 + s;
            const float* hprev = (t == 0) ? nullptr : out + (size_t)(t - 1) * B_DIM * H_DIM;
            const float* gxs = gx + (size_t)s * B_DIM * G_DIM;
            gru_zr_mfma<<<dim3(32, 8), 256, 0, stream>>>(
                gxs, hprev, h_hi, h_lo, whT_hi, whT_lo, zbuf, rh_hi, rh_lo);
            gru_a_mfma<<<dim3(16, 8), 256, 0, stream>>>(
                gxs, hprev, rh_hi, rh_lo, zbuf, whT_hi, whT_lo,
                out + (size_t)t * B_DIM * H_DIM, h_hi, h_lo);
        }
    }
}